// Round 5
// baseline (169.923 us; speedup 1.0000x reference)
//
#include <hip/hip_runtime.h>
#include <math.h>

#define IN_DIM 1024
#define OUT_DIM 1024
#define NROWS 8192
#define XSTRIDE 1025   // x rows: 1024 feats + 1 phase

typedef __attribute__((ext_vector_type(8))) short bf16x8;
typedef __attribute__((ext_vector_type(4))) float f32x4;

static __device__ __forceinline__ unsigned f2bf(float f) {
  union { float f; unsigned u; } v; v.f = f;
  unsigned u = v.u;
  return (u + 0x7fffu + ((u >> 16) & 1u)) >> 16;  // RTNE
}

// ---- prep: unchanged.
//  blocks [0,2048):    W(4,1024,1024) f32 -> Wall bf16, row g=(o&15)|(k<<4)|((o>>4)<<6)
//  blocks [2048,10240): feats -> F bf16 (8192x1024); thread 0 also writes coef[b] (float4)
__global__ __launch_bounds__(256) void prep_kernel(
    const float* __restrict__ x, const float* __restrict__ W,
    unsigned short* __restrict__ Wb, unsigned short* __restrict__ F,
    float* __restrict__ coef)
{
  const int blk = blockIdx.x;
  if (blk < 2048) {
    const int t = blk * 256 + threadIdx.x;
    const int flat = t * 8;                    // 8 elems of W
    const int k = flat >> 20;
    const int o = (flat >> 10) & 1023;
    const int i = flat & 1023;                 // multiple of 8
    const float4 fa = *reinterpret_cast<const float4*>(W + flat);
    const float4 fb = *reinterpret_cast<const float4*>(W + flat + 4);
    uint4 pk;
    pk.x = f2bf(fa.x) | (f2bf(fa.y) << 16);
    pk.y = f2bf(fa.z) | (f2bf(fa.w) << 16);
    pk.z = f2bf(fb.x) | (f2bf(fb.y) << 16);
    pk.w = f2bf(fb.z) | (f2bf(fb.w) << 16);
    const int g = (o & 15) | (k << 4) | ((o >> 4) << 6);
    *reinterpret_cast<uint4*>(Wb + (size_t)g * 1024 + i) = pk;
  } else {
    const int b = blk - 2048;
    const float* xr = x + (size_t)b * XSTRIDE;
    const int i = threadIdx.x * 4;
    ushort4 vv;
    vv.x = (unsigned short)f2bf(xr[i]);     vv.y = (unsigned short)f2bf(xr[i + 1]);
    vv.z = (unsigned short)f2bf(xr[i + 2]); vv.w = (unsigned short)f2bf(xr[i + 3]);
    *reinterpret_cast<ushort4*>(F + (size_t)b * 1024 + i) = vv;
    if (threadIdx.x == 0) {
      const float ps = 4.0f * xr[IN_DIM];
      const int ip = (int)ps;            // trunc, ps in [0,4)
      const int i1 = ip & 3;
      const float mu = ps - (float)ip;
      const float mu2 = mu * mu, mu3 = mu2 * mu;
      const float c0 = -0.5f * mu3 +        mu2 - 0.5f * mu;
      const float c1 =  1.5f * mu3 - 2.5f * mu2 + 1.0f;
      const float c2 = -1.5f * mu3 + 2.0f * mu2 + 0.5f * mu;
      const float c3 =  0.5f * mu3 - 0.5f * mu2;
      const int d0 = (0-i1)&3, d1 = (1-i1)&3, d2 = (2-i1)&3, d3 = (3-i1)&3;
      float4 cv;
      cv.x = d0==0 ? c1 : d0==1 ? c2 : d0==2 ? c3 : c0;
      cv.y = d1==0 ? c1 : d1==1 ? c2 : d1==2 ? c3 : c0;
      cv.z = d2==0 ? c1 : d2==1 ? c2 : d2==2 ? c3 : c0;
      cv.w = d3==0 ? c1 : d3==1 ? c2 : d3==2 ? c3 : c0;
      *reinterpret_cast<float4*>(coef + (size_t)b * 4) = cv;
    }
  }
}

// ---- GEMM: C'(8192 x 4096) = F . Wall^T. Proven 2-barrier single-buffer
// structure; 2-wave blocks for max independent barrier groups per CU:
// block 128M x 128N(g), 2 waves side-by-side in N, wave tile 128x64
// (acc[8][4] = 128 AGPR). LDS 32 KB; ~220 regs/lane -> 4 blocks/CU static.
// Same low LDS-read traffic as round-4 (2.23e-5 B/FLOP) but 2x the
// independent blocks -> better implicit LDS/MFMA overlap (m114 mechanism).
#define BM 128
#define BN 128   // g-columns = 32 o's x 4 knots
#define BK 64

__global__ __launch_bounds__(128, 2) void gemm_kernel(
    const unsigned short* __restrict__ F,    // 8192x1024 bf16
    const unsigned short* __restrict__ Wb,   // 4096x1024 bf16, g-layout
    const float* __restrict__ coef,          // 8192x4 f32
    const float* __restrict__ bias,          // 4x1024 f32
    float* __restrict__ out)
{
  __shared__ unsigned short As[BM * BK];   // 16 KB
  __shared__ unsigned short Bs[BN * BK];   // 16 KB  (32 KB total)

  const int tid  = threadIdx.x;
  const int wave = tid >> 6;               // 0..1
  const int lane = tid & 63;
  const int row0  = blockIdx.y * BM;
  const int col0g = blockIdx.x * BN;       // g-row base of Wall

  // staging: thread t -> LDS slot t*16B; XOR chunk swizzle on global source
  const int srow = tid >> 3;               // 0..15
  const int scc  = tid & 7;
  const int sgc  = (scc ^ (srow & 7)) * 8; // r = srow + it*16 keeps r&7 == srow&7

  const int wc = wave * 64;                // 2 N-waves; both cover all 128 rows
  const int fm = lane & 15;
  const int fq = lane >> 4;

  f32x4 acc[8][4];   // [mi][ni=knot] -> 128 AGPR
  const f32x4 zero = {0.f, 0.f, 0.f, 0.f};
  #pragma unroll
  for (int a = 0; a < 8; a++)
    #pragma unroll
    for (int b = 0; b < 4; b++)
      acc[a][b] = zero;

  const unsigned short* Abase = F  + (size_t)row0  * 1024;
  const unsigned short* Bbase = Wb + (size_t)col0g * 1024;

  for (int kb = 0; kb < 1024; kb += BK) {
    #pragma unroll
    for (int it = 0; it < 8; it++) {       // A: 128 rows (16 rows/iter)
      const int r = srow + it * 16;
      __builtin_amdgcn_global_load_lds(
          (const __attribute__((address_space(1))) void*)(Abase + (size_t)r * 1024 + kb + sgc),
          (__attribute__((address_space(3))) void*)(As + r * BK + scc * 8), 16, 0, 0);
    }
    #pragma unroll
    for (int it = 0; it < 8; it++) {       // B: 128 g-rows
      const int r = srow + it * 16;
      __builtin_amdgcn_global_load_lds(
          (const __attribute__((address_space(1))) void*)(Bbase + (size_t)r * 1024 + kb + sgc),
          (__attribute__((address_space(3))) void*)(Bs + r * BK + scc * 8), 16, 0, 0);
    }
    __syncthreads();

    #pragma unroll
    for (int kk = 0; kk < BK; kk += 32) {
      bf16x8 af[8], bfr[4];
      #pragma unroll
      for (int mi = 0; mi < 8; mi++) {
        const int r  = mi * 16 + fm;
        const int lc = ((kk >> 3) + fq) ^ (fm & 7);
        af[mi] = *reinterpret_cast<const bf16x8*>(As + r * BK + lc * 8);
      }
      #pragma unroll
      for (int ni = 0; ni < 4; ni++) {
        const int r  = wc + ni * 16 + fm;
        const int lc = ((kk >> 3) + fq) ^ (fm & 7);
        bfr[ni] = *reinterpret_cast<const bf16x8*>(Bs + r * BK + lc * 8);
      }
      #pragma unroll
      for (int mi = 0; mi < 8; mi++)
        #pragma unroll
        for (int ni = 0; ni < 4; ni++)
          acc[mi][ni] = __builtin_amdgcn_mfma_f32_16x16x32_bf16(
              af[mi], bfr[ni], acc[mi][ni], 0, 0, 0);
    }
    __syncthreads();
  }

  // ---- epilogue: v = sum_k c_k*(acc_k + bias_k[o]); fast elu; dense store
  const int o = fm + 16 * (2 * blockIdx.x + wave);   // this lane's output column
  const float b0 = bias[o];
  const float b1 = bias[OUT_DIM + o];
  const float b2 = bias[2 * OUT_DIM + o];
  const float b3 = bias[3 * OUT_DIM + o];
  #pragma unroll
  for (int mi = 0; mi < 8; mi++) {
    #pragma unroll
    for (int r = 0; r < 4; r++) {
      const int rloc = mi * 16 + (fq << 2) + r;
      const float4 c = *reinterpret_cast<const float4*>(coef + (size_t)(row0 + rloc) * 4);
      float v = c.x * (acc[mi][0][r] + b0)
              + c.y * (acc[mi][1][r] + b1)
              + c.z * (acc[mi][2][r] + b2)
              + c.w * (acc[mi][3][r] + b3);
      // elu(alpha=1): exp(v)-1 via hw v_exp_f32; abs err ~1e-7 << 4.3e-3 threshold
      const float e = __expf(v) - 1.0f;
      v = (v > 0.0f) ? v : e;
      out[(size_t)(row0 + rloc) * OUT_DIM + o] = v;
    }
  }
}

extern "C" void kernel_launch(void* const* d_in, const int* in_sizes, int n_in,
                              void* d_out, int out_size, void* d_ws, size_t ws_size,
                              hipStream_t stream) {
  const float* x  = (const float*)d_in[0];   // (8192, 1025)
  const float* wk = (const float*)d_in[1];   // (4, 1024, 1024)
  const float* bk = (const float*)d_in[2];   // (4, 1024)
  float* out = (float*)d_out;                // (8192, 1024) fp32

  char* ws = (char*)d_ws;
  unsigned short* Wb = (unsigned short*)ws;                   // 8 MB
  unsigned short* F  = (unsigned short*)(ws + (8u << 20));    // 16 MB
  float* coef        = (float*)(ws + (24u << 20));            // 128 KB

  hipLaunchKernelGGL(prep_kernel, dim3(2048 + NROWS), dim3(256), 0, stream,
                     x, wk, Wb, F, coef);
  hipLaunchKernelGGL(gemm_kernel, dim3(4096 / BN, NROWS / BM), dim3(128), 0, stream,
                     F, Wb, coef, bk, out);
}

// Round 7
// 164.005 us; speedup vs baseline: 1.0361x; 1.0361x over previous
//
#include <hip/hip_runtime.h>
#include <math.h>

#define IN_DIM 1024
#define OUT_DIM 1024
#define NROWS 8192
#define XSTRIDE 1025   // x rows: 1024 feats + 1 phase

typedef __attribute__((ext_vector_type(8))) short bf16x8;
typedef __attribute__((ext_vector_type(16))) float f32x16;

static __device__ __forceinline__ unsigned f2bf(float f) {
  union { float f; unsigned u; } v; v.f = f;
  unsigned u = v.u;
  return (u + 0x7fffu + ((u >> 16) & 1u)) >> 16;  // RTNE
}

// ---- prep:
//  blocks [0,2048):    W(4,1024,1024) f32 -> Wall bf16, row g=(o&31)|(k<<5)|((o>>5)<<7)
//                      (32-wide o-groups so one 32x32 MFMA B-fragment = one knot)
//  blocks [2048,10240): feats -> F bf16 (8192x1024); thread 0 also writes coef[b] (float4)
__global__ __launch_bounds__(256) void prep_kernel(
    const float* __restrict__ x, const float* __restrict__ W,
    unsigned short* __restrict__ Wb, unsigned short* __restrict__ F,
    float* __restrict__ coef)
{
  const int blk = blockIdx.x;
  if (blk < 2048) {
    const int t = blk * 256 + threadIdx.x;
    const int flat = t * 8;                    // 8 elems of W
    const int k = flat >> 20;
    const int o = (flat >> 10) & 1023;
    const int i = flat & 1023;                 // multiple of 8
    const float4 fa = *reinterpret_cast<const float4*>(W + flat);
    const float4 fb = *reinterpret_cast<const float4*>(W + flat + 4);
    uint4 pk;
    pk.x = f2bf(fa.x) | (f2bf(fa.y) << 16);
    pk.y = f2bf(fa.z) | (f2bf(fa.w) << 16);
    pk.z = f2bf(fb.x) | (f2bf(fb.y) << 16);
    pk.w = f2bf(fb.z) | (f2bf(fb.w) << 16);
    const int g = (o & 31) | (k << 5) | ((o >> 5) << 7);
    *reinterpret_cast<uint4*>(Wb + (size_t)g * 1024 + i) = pk;
  } else {
    const int b = blk - 2048;
    const float* xr = x + (size_t)b * XSTRIDE;
    const int i = threadIdx.x * 4;
    ushort4 vv;
    vv.x = (unsigned short)f2bf(xr[i]);     vv.y = (unsigned short)f2bf(xr[i + 1]);
    vv.z = (unsigned short)f2bf(xr[i + 2]); vv.w = (unsigned short)f2bf(xr[i + 3]);
    *reinterpret_cast<ushort4*>(F + (size_t)b * 1024 + i) = vv;
    if (threadIdx.x == 0) {
      const float ps = 4.0f * xr[IN_DIM];
      const int ip = (int)ps;            // trunc, ps in [0,4)
      const int i1 = ip & 3;
      const float mu = ps - (float)ip;
      const float mu2 = mu * mu, mu3 = mu2 * mu;
      const float c0 = -0.5f * mu3 +        mu2 - 0.5f * mu;
      const float c1 =  1.5f * mu3 - 2.5f * mu2 + 1.0f;
      const float c2 = -1.5f * mu3 + 2.0f * mu2 + 0.5f * mu;
      const float c3 =  0.5f * mu3 - 0.5f * mu2;
      const int d0 = (0-i1)&3, d1 = (1-i1)&3, d2 = (2-i1)&3, d3 = (3-i1)&3;
      float4 cv;
      cv.x = d0==0 ? c1 : d0==1 ? c2 : d0==2 ? c3 : c0;
      cv.y = d1==0 ? c1 : d1==1 ? c2 : d1==2 ? c3 : c0;
      cv.z = d2==0 ? c1 : d2==1 ? c2 : d2==2 ? c3 : c0;
      cv.w = d3==0 ? c1 : d3==1 ? c2 : d3==2 ? c3 : c0;
      *reinterpret_cast<float4*>(coef + (size_t)b * 4) = cv;
    }
  }
}

// ---- GEMM: C'(8192 x 4096) = F . Wall^T. Proven 2-barrier single-buffer
// structure, switched to the faster 32x32x16 MFMA pipe (2495 vs 2075 TF
// ubench; half the instruction count -> more issue slack for ds_read).
// Block 256M x 128N(g), 4 waves stacked in M; wave tile 64M x 128N =
// 2x4 fragments of 32x32 (acc = 8 x f32x16 = 128 AGPR). Fragment nj = knot.
// ds_read: 24 b128 per 64 MFMA-16-equiv (best ratio measured, round 4).
// 48 KB LDS -> 3 blocks/CU; ~172 regs -> ~11 waves/CU.
#define BM 256
#define BN 128   // g-columns = 32 o's x 4 knots
#define BK 64

__global__ __launch_bounds__(256, 2) void gemm_kernel(
    const unsigned short* __restrict__ F,    // 8192x1024 bf16
    const unsigned short* __restrict__ Wb,   // 4096x1024 bf16, g-layout
    const float* __restrict__ coef,          // 8192x4 f32
    const float* __restrict__ bias,          // 4x1024 f32
    float* __restrict__ out)
{
  __shared__ unsigned short As[BM * BK];   // 32 KB
  __shared__ unsigned short Bs[BN * BK];   // 16 KB  (48 KB total)

  const int tid  = threadIdx.x;
  const int wave = tid >> 6;               // 0..3
  const int lane = tid & 63;
  const int row0  = blockIdx.y * BM;
  const int col0g = blockIdx.x * BN;       // g-row base of Wall

  // staging: thread t -> LDS slot t*16B; XOR chunk swizzle on global source
  const int srow = tid >> 3;               // 0..31
  const int scc  = tid & 7;
  const int sgc  = (scc ^ (srow & 7)) * 8; // r = srow + it*32 keeps r&7 == srow&7

  const int wr = wave * 64;                // 4 M-waves; each covers all 128 g-cols
  const int lm = lane & 31;
  const int hi = lane >> 5;

  f32x16 acc[2][4];   // [mi][nj=knot] -> 128 AGPR
  #pragma unroll
  for (int a = 0; a < 2; a++)
    #pragma unroll
    for (int b = 0; b < 4; b++)
      acc[a][b] = (f32x16)(0.0f);

  const unsigned short* Abase = F  + (size_t)row0  * 1024;
  const unsigned short* Bbase = Wb + (size_t)col0g * 1024;

  for (int kb = 0; kb < 1024; kb += BK) {
    #pragma unroll
    for (int it = 0; it < 8; it++) {       // A: 256 rows (32 rows/iter)
      const int r = srow + it * 32;
      __builtin_amdgcn_global_load_lds(
          (const __attribute__((address_space(1))) void*)(Abase + (size_t)r * 1024 + kb + sgc),
          (__attribute__((address_space(3))) void*)(As + r * BK + scc * 8), 16, 0, 0);
    }
    #pragma unroll
    for (int it = 0; it < 4; it++) {       // B: 128 g-rows
      const int r = srow + it * 32;
      __builtin_amdgcn_global_load_lds(
          (const __attribute__((address_space(1))) void*)(Bbase + (size_t)r * 1024 + kb + sgc),
          (__attribute__((address_space(3))) void*)(Bs + r * BK + scc * 8), 16, 0, 0);
    }
    __syncthreads();

    #pragma unroll
    for (int ks = 0; ks < 4; ks++) {       // 4 K-steps of 16
      const int lc = ((2 * ks + hi) ^ (lm & 7)) * 8;  // chunk swizzle (r&7 == lm&7)
      bf16x8 a[2], b[4];
      #pragma unroll
      for (int mi = 0; mi < 2; mi++)
        a[mi] = *reinterpret_cast<const bf16x8*>(As + (wr + mi * 32 + lm) * BK + lc);
      #pragma unroll
      for (int nj = 0; nj < 4; nj++)
        b[nj] = *reinterpret_cast<const bf16x8*>(Bs + (nj * 32 + lm) * BK + lc);
      #pragma unroll
      for (int mi = 0; mi < 2; mi++)
        #pragma unroll
        for (int nj = 0; nj < 4; nj++)
          acc[mi][nj] = __builtin_amdgcn_mfma_f32_32x32x16_bf16(
              a[mi], b[nj], acc[mi][nj], 0, 0, 0);
    }
    __syncthreads();
  }

  // ---- epilogue: v = sum_k c_k*(acc_k + bias_k[o]); fast elu; dense store
  // 32x32 C layout: col = lane&31, row = (reg&3) + 8*(reg>>2) + 4*(lane>>5)
  const int o = (blockIdx.x << 5) + lm;    // this lane's output column
  const float b0 = bias[o];
  const float b1 = bias[OUT_DIM + o];
  const float b2 = bias[2 * OUT_DIM + o];
  const float b3 = bias[3 * OUT_DIM + o];
  #pragma unroll
  for (int mi = 0; mi < 2; mi++) {
    #pragma unroll
    for (int reg = 0; reg < 16; reg++) {
      const int rloc = wr + mi * 32 + (reg & 3) + 8 * (reg >> 2) + 4 * hi;
      const float4 c = *reinterpret_cast<const float4*>(coef + (size_t)(row0 + rloc) * 4);
      float v = c.x * (acc[mi][0][reg] + b0)
              + c.y * (acc[mi][1][reg] + b1)
              + c.z * (acc[mi][2][reg] + b2)
              + c.w * (acc[mi][3][reg] + b3);
      // elu(alpha=1): exp(v)-1 via hw v_exp_f32; abs err ~1e-7 << 4.3e-3 threshold
      const float e = __expf(v) - 1.0f;
      v = (v > 0.0f) ? v : e;
      out[(size_t)(row0 + rloc) * OUT_DIM + o] = v;
    }
  }
}

extern "C" void kernel_launch(void* const* d_in, const int* in_sizes, int n_in,
                              void* d_out, int out_size, void* d_ws, size_t ws_size,
                              hipStream_t stream) {
  const float* x  = (const float*)d_in[0];   // (8192, 1025)
  const float* wk = (const float*)d_in[1];   // (4, 1024, 1024)
  const float* bk = (const float*)d_in[2];   // (4, 1024)
  float* out = (float*)d_out;                // (8192, 1024) fp32

  char* ws = (char*)d_ws;
  unsigned short* Wb = (unsigned short*)ws;                   // 8 MB
  unsigned short* F  = (unsigned short*)(ws + (8u << 20));    // 16 MB
  float* coef        = (float*)(ws + (24u << 20));            // 128 KB

  hipLaunchKernelGGL(prep_kernel, dim3(2048 + NROWS), dim3(256), 0, stream,
                     x, wk, Wb, F, coef);
  hipLaunchKernelGGL(gemm_kernel, dim3(4096 / BN, NROWS / BM), dim3(256), 0, stream,
                     F, Wb, coef, bk, out);
}

// Round 8
// 159.349 us; speedup vs baseline: 1.0664x; 1.0292x over previous
//
#include <hip/hip_runtime.h>
#include <math.h>

#define IN_DIM 1024
#define OUT_DIM 1024
#define NROWS 8192
#define XSTRIDE 1025   // x rows: 1024 feats + 1 phase

typedef __attribute__((ext_vector_type(8))) short bf16x8;
typedef __attribute__((ext_vector_type(4))) float f32x4;

static __device__ __forceinline__ unsigned f2bf(float f) {
  union { float f; unsigned u; } v; v.f = f;
  unsigned u = v.u;
  return (u + 0x7fffu + ((u >> 16) & 1u)) >> 16;  // RTNE
}

// ---- prep:
//  blocks [0,2048):    W(4,1024,1024) f32 -> Wall bf16, row g=(o&15)|(k<<4)|((o>>4)<<6)
//  blocks [2048,10240): feats -> F bf16 (8192x1024); thread 0 also writes coef[b] (float4)
__global__ __launch_bounds__(256) void prep_kernel(
    const float* __restrict__ x, const float* __restrict__ W,
    unsigned short* __restrict__ Wb, unsigned short* __restrict__ F,
    float* __restrict__ coef)
{
  const int blk = blockIdx.x;
  if (blk < 2048) {
    const int t = blk * 256 + threadIdx.x;
    const int flat = t * 8;                    // 8 elems of W
    const int k = flat >> 20;
    const int o = (flat >> 10) & 1023;
    const int i = flat & 1023;                 // multiple of 8
    const float4 fa = *reinterpret_cast<const float4*>(W + flat);
    const float4 fb = *reinterpret_cast<const float4*>(W + flat + 4);
    uint4 pk;
    pk.x = f2bf(fa.x) | (f2bf(fa.y) << 16);
    pk.y = f2bf(fa.z) | (f2bf(fa.w) << 16);
    pk.z = f2bf(fb.x) | (f2bf(fb.y) << 16);
    pk.w = f2bf(fb.z) | (f2bf(fb.w) << 16);
    const int g = (o & 15) | (k << 4) | ((o >> 4) << 6);
    *reinterpret_cast<uint4*>(Wb + (size_t)g * 1024 + i) = pk;
  } else {
    const int b = blk - 2048;
    const float* xr = x + (size_t)b * XSTRIDE;
    const int i = threadIdx.x * 4;
    ushort4 vv;
    vv.x = (unsigned short)f2bf(xr[i]);     vv.y = (unsigned short)f2bf(xr[i + 1]);
    vv.z = (unsigned short)f2bf(xr[i + 2]); vv.w = (unsigned short)f2bf(xr[i + 3]);
    *reinterpret_cast<ushort4*>(F + (size_t)b * 1024 + i) = vv;
    if (threadIdx.x == 0) {
      const float ps = 4.0f * xr[IN_DIM];
      const int ip = (int)ps;            // trunc, ps in [0,4)
      const int i1 = ip & 3;
      const float mu = ps - (float)ip;
      const float mu2 = mu * mu, mu3 = mu2 * mu;
      const float c0 = -0.5f * mu3 +        mu2 - 0.5f * mu;
      const float c1 =  1.5f * mu3 - 2.5f * mu2 + 1.0f;
      const float c2 = -1.5f * mu3 + 2.0f * mu2 + 0.5f * mu;
      const float c3 =  0.5f * mu3 - 0.5f * mu2;
      const int d0 = (0-i1)&3, d1 = (1-i1)&3, d2 = (2-i1)&3, d3 = (3-i1)&3;
      float4 cv;
      cv.x = d0==0 ? c1 : d0==1 ? c2 : d0==2 ? c3 : c0;
      cv.y = d1==0 ? c1 : d1==1 ? c2 : d1==2 ? c3 : c0;
      cv.z = d2==0 ? c1 : d2==1 ? c2 : d2==2 ? c3 : c0;
      cv.w = d3==0 ? c1 : d3==1 ? c2 : d3==2 ? c3 : c0;
      *reinterpret_cast<float4*>(coef + (size_t)b * 4) = cv;
    }
  }
}

// ---- GEMM: C'(8192 x 4096) = F . Wall^T, knots interleaved in N so that
// fragment ni == knot index; cubic combine + bias + elu fused per-lane in
// epilogue. Round-0 structure (best measured: 68.4us, 1004 TF, conflicts 0)
// + bijective XCD-aware 2D-chunk block swizzle (T1): 8 chunks of 16x16
// tiles, one per XCD -> per-XCD L2 working set 16 A-panels + 16 B-panels
// (8 MB) instead of all-64 A-panels thrash.
#define BM 128
#define BN 128   // g-columns = 32 o's x 4 knots
#define BK 64

__global__ __launch_bounds__(256, 4) void gemm_kernel(
    const unsigned short* __restrict__ F,    // 8192x1024 bf16
    const unsigned short* __restrict__ Wb,   // 4096x1024 bf16, g-layout
    const float* __restrict__ coef,          // 8192x4 f32
    const float* __restrict__ bias,          // 4x1024 f32
    float* __restrict__ out)
{
  __shared__ unsigned short As[BM * BK];   // 16 KB
  __shared__ unsigned short Bs[BN * BK];   // 16 KB  (32 KB total)

  // XCD swizzle: grid is 32(x) x 64(y) = 2048 blocks, default linear id is
  // x-major. Remap so XCD c (= lin%8 under round-robin dispatch) owns one
  // contiguous 16x16 tile chunk: c -> (cx,cy) = (c&1, c>>1).
  const int lin = blockIdx.y * 32 + blockIdx.x;
  const int xcd = lin & 7;
  const int idx = lin >> 3;                // 0..255 within chunk
  const int bx  = (xcd & 1) * 16 + (idx & 15);
  const int by  = (xcd >> 1) * 16 + (idx >> 4);

  const int tid  = threadIdx.x;
  const int wave = tid >> 6;
  const int lane = tid & 63;
  const int row0  = by * BM;
  const int col0g = bx * BN;               // g-row base of Wall

  // staging: thread t -> LDS slot t*16B; XOR chunk swizzle on global source
  const int srow = tid >> 3;
  const int scc  = tid & 7;
  const int sgc  = (scc ^ (srow & 7)) * 8;

  const int wr = (wave >> 1) * 64;
  const int wc = (wave & 1) * 64;
  const int fm = lane & 15;
  const int fq = lane >> 4;

  f32x4 acc[4][4];   // [mi][ni=knot]
  const f32x4 zero = {0.f, 0.f, 0.f, 0.f};
  #pragma unroll
  for (int a = 0; a < 4; a++)
    #pragma unroll
    for (int b = 0; b < 4; b++)
      acc[a][b] = zero;

  const unsigned short* Abase = F  + (size_t)row0  * 1024;
  const unsigned short* Bbase = Wb + (size_t)col0g * 1024;

  for (int kb = 0; kb < 1024; kb += BK) {
    #pragma unroll
    for (int it = 0; it < 4; it++) {
      const int r = srow + it * 32;   // (r&7)==(srow&7): swizzle invariant
      __builtin_amdgcn_global_load_lds(
          (const __attribute__((address_space(1))) void*)(Abase + (size_t)r * 1024 + kb + sgc),
          (__attribute__((address_space(3))) void*)(As + r * BK + scc * 8), 16, 0, 0);
      __builtin_amdgcn_global_load_lds(
          (const __attribute__((address_space(1))) void*)(Bbase + (size_t)r * 1024 + kb + sgc),
          (__attribute__((address_space(3))) void*)(Bs + r * BK + scc * 8), 16, 0, 0);
    }
    __syncthreads();

    #pragma unroll
    for (int kk = 0; kk < BK; kk += 32) {
      bf16x8 af[4], bfr[4];
      #pragma unroll
      for (int mi = 0; mi < 4; mi++) {
        const int r  = wr + mi * 16 + fm;
        const int lc = ((kk >> 3) + fq) ^ (fm & 7);
        af[mi] = *reinterpret_cast<const bf16x8*>(As + r * BK + lc * 8);
      }
      #pragma unroll
      for (int ni = 0; ni < 4; ni++) {
        const int r  = wc + ni * 16 + fm;
        const int lc = ((kk >> 3) + fq) ^ (fm & 7);
        bfr[ni] = *reinterpret_cast<const bf16x8*>(Bs + r * BK + lc * 8);
      }
      #pragma unroll
      for (int mi = 0; mi < 4; mi++)
        #pragma unroll
        for (int ni = 0; ni < 4; ni++)
          acc[mi][ni] = __builtin_amdgcn_mfma_f32_16x16x32_bf16(
              af[mi], bfr[ni], acc[mi][ni], 0, 0, 0);
    }
    __syncthreads();
  }

  // ---- epilogue: v = sum_k c_k*(acc_k + bias_k[o]); fast elu; dense store
  const int o = fm + 16 * (2 * bx + (wave & 1));   // this lane's output column
  const float b0 = bias[o];
  const float b1 = bias[OUT_DIM + o];
  const float b2 = bias[2 * OUT_DIM + o];
  const float b3 = bias[3 * OUT_DIM + o];
  #pragma unroll
  for (int mi = 0; mi < 4; mi++) {
    #pragma unroll
    for (int r = 0; r < 4; r++) {
      const int rloc = wr + mi * 16 + (fq << 2) + r;
      const float4 c = *reinterpret_cast<const float4*>(coef + (size_t)(row0 + rloc) * 4);
      float v = c.x * (acc[mi][0][r] + b0)
              + c.y * (acc[mi][1][r] + b1)
              + c.z * (acc[mi][2][r] + b2)
              + c.w * (acc[mi][3][r] + b3);
      // elu(alpha=1): exp(v)-1 via hw v_exp_f32; abs err ~1e-7 << 4.3e-3 threshold
      const float e = __expf(v) - 1.0f;
      v = (v > 0.0f) ? v : e;
      out[(size_t)(row0 + rloc) * OUT_DIM + o] = v;
    }
  }
}

extern "C" void kernel_launch(void* const* d_in, const int* in_sizes, int n_in,
                              void* d_out, int out_size, void* d_ws, size_t ws_size,
                              hipStream_t stream) {
  const float* x  = (const float*)d_in[0];   // (8192, 1025)
  const float* wk = (const float*)d_in[1];   // (4, 1024, 1024)
  const float* bk = (const float*)d_in[2];   // (4, 1024)
  float* out = (float*)d_out;                // (8192, 1024) fp32

  char* ws = (char*)d_ws;
  unsigned short* Wb = (unsigned short*)ws;                   // 8 MB
  unsigned short* F  = (unsigned short*)(ws + (8u << 20));    // 16 MB
  float* coef        = (float*)(ws + (24u << 20));            // 128 KB

  hipLaunchKernelGGL(prep_kernel, dim3(2048 + NROWS), dim3(256), 0, stream,
                     x, wk, Wb, F, coef);
  hipLaunchKernelGGL(gemm_kernel, dim3(4096 / BN, NROWS / BM), dim3(256), 0, stream,
                     F, Wb, coef, bk, out);
}